// Round 10
// baseline (426.570 us; speedup 1.0000x reference)
//
#include <hip/hip_runtime.h>
#include <hip/hip_bf16.h>

typedef unsigned int uint32;
typedef unsigned short ushort16;

using bf16x8 = __attribute__((ext_vector_type(8))) short;
using f32x4  = __attribute__((ext_vector_type(4))) float;

#define N_MATN 100000
#define N_ELEMN 118
#define F_MATN 128
#define F_ELEMN 64
#define HIDN 128
#define NHEAD 8
#define OUTC 64
#define NSTRIPS 6250              // 100000 / 16

#define MATBLK 1024               // mat-projection blocks inside proj_all
#define CNTBLK 128                // bucket-count blocks inside proj_all

// bucketed scatter params
#define SH 8                      // 256 dst nodes per bucket
#define NBK 391                   // ceil(100000/256)
#define BCH 8192                  // edges per bin chunk (368 chunks > 256 CUs)
#define LOCN 6144                 // place_pass LDS CSR segment capacity

__device__ __forceinline__ float blo(uint32 u){ return __uint_as_float(u << 16); }
__device__ __forceinline__ float bhi(uint32 u){ return __uint_as_float(u & 0xffff0000u); }
__device__ __forceinline__ ushort16 f2bf(float f){
    uint32 u = __float_as_uint(f);
    uint32 r = u + 0x7FFFu + ((u >> 16) & 1u);   // RNE
    return (ushort16)(r >> 16);
}
__device__ __forceinline__ uint32 pack2(float a, float b){
    return (uint32)f2bf(a) | ((uint32)f2bf(b) << 16);
}
__device__ __forceinline__ bf16x8 cvt8(const float* __restrict__ p){
    bf16x8 r;
    #pragma unroll
    for(int j=0;j<8;j++) r[j] = (short)f2bf(p[j]);
    return r;
}

// ---------------- fused: elem-proj [0,118) | mat-proj [118,1142) | bucket-count [1142,1270)
__global__ __launch_bounds__(256) void proj_all(
    const float* __restrict__ xe, const float* __restrict__ We,
    const float* __restrict__ be, const float* __restrict__ a_se,
    ushort16* __restrict__ h_elem, float* __restrict__ asrc_em,
    const float* __restrict__ x, const float* __restrict__ W,
    const float* __restrict__ bias,
    const float* __restrict__ a_de, const float* __restrict__ a_sm, const float* __restrict__ a_dm,
    ushort16* __restrict__ h,
    float* __restrict__ adst_em, float* __restrict__ asrc_mm, float* __restrict__ adst_mm,
    const int* __restrict__ dst_em, int nE_em, int* __restrict__ bcnt_em,
    const int* __restrict__ dst_mm, int nE_mm, int* __restrict__ bcnt_mm)
{
    int tid = threadIdx.x;
    if(blockIdx.x < N_ELEMN){
        // ---- elem projection (one block per node, 128 active threads)
        __shared__ float xr[F_ELEMN];
        int n = blockIdx.x, c = tid;
        if(c < 16) ((float4*)xr)[c] = ((const float4*)(xe + n*F_ELEMN))[c];
        __syncthreads();
        if(c < 128){
            const float4* Wr = (const float4*)(We + c*F_ELEMN);
            float acc = 0.f;
            #pragma unroll 4
            for(int i=0;i<16;i++){
                float4 w = Wr[i];
                acc += xr[4*i]*w.x + xr[4*i+1]*w.y + xr[4*i+2]*w.z + xr[4*i+3]*w.w;
            }
            acc += be[c];
            h_elem[n*HIDN + c] = f2bf(acc);
            float p = acc * a_se[c];
            #pragma unroll
            for(int m=8;m>=1;m>>=1) p += __shfl_xor(p, m, 16);
            if((c&15)==0) asrc_em[n*NHEAD + (c>>4)] = p;
        }
        return;
    }
    if(blockIdx.x >= N_ELEMN + MATBLK){
        // ---- bucket-count (LDS histograms, int4 streaming)
        __shared__ int he[NBK], hm[NBK];
        for(int i=tid;i<NBK;i+=256){ he[i]=0; hm[i]=0; }
        __syncthreads();
        int cb = blockIdx.x - (N_ELEMN + MATBLK);
        int gt = cb*256 + tid;
        int st = CNTBLK*256;
        {
            int n4 = nE_em >> 2;
            const int4* d4 = (const int4*)dst_em;
            for(int i = gt; i < n4; i += st){
                int4 v = d4[i];
                atomicAdd(&he[v.x>>SH],1); atomicAdd(&he[v.y>>SH],1);
                atomicAdd(&he[v.z>>SH],1); atomicAdd(&he[v.w>>SH],1);
            }
            for(int i = (n4<<2) + gt; i < nE_em; i += st) atomicAdd(&he[dst_em[i]>>SH],1);
        }
        {
            int n4 = nE_mm >> 2;
            const int4* d4 = (const int4*)dst_mm;
            for(int i = gt; i < n4; i += st){
                int4 v = d4[i];
                atomicAdd(&hm[v.x>>SH],1); atomicAdd(&hm[v.y>>SH],1);
                atomicAdd(&hm[v.z>>SH],1); atomicAdd(&hm[v.w>>SH],1);
            }
            for(int i = (n4<<2) + gt; i < nE_mm; i += st) atomicAdd(&hm[dst_mm[i]>>SH],1);
        }
        __syncthreads();
        for(int j=tid;j<NBK;j+=256){
            int a = he[j], b = hm[j];
            if(a) atomicAdd(&bcnt_em[j], a);
            if(b) atomicAdd(&bcnt_mm[j], b);
        }
        return;
    }
    // ---- mat projection (MFMA 16x16x32 bf16)
    int wv = tid >> 6, lane = tid & 63, quad = lane >> 4, sl = lane & 15;
    bf16x8 B[2][4];
    float bc[2], ade[2], asv[2], adv[2];
    #pragma unroll
    for(int i=0;i<2;i++){
        int c = (2*wv+i)*16 + sl;
        const float* wr = W + c*F_MATN;
        #pragma unroll
        for(int ks=0;ks<4;ks++) B[i][ks] = cvt8(wr + ks*32 + quad*8);
        bc[i] = bias[c]; ade[i] = a_de[c]; asv[i] = a_sm[c]; adv[i] = a_dm[c];
    }
    for(int s = blockIdx.x - N_ELEMN; s < NSTRIPS; s += MATBLK){
        int n0 = s*16;
        const float* xrow = x + (size_t)(n0+sl)*F_MATN;
        bf16x8 A[4];
        #pragma unroll
        for(int ks=0;ks<4;ks++) A[ks] = cvt8(xrow + ks*32 + quad*8);
        f32x4 acc[2];
        #pragma unroll
        for(int i=0;i<2;i++){ acc[i][0]=0.f; acc[i][1]=0.f; acc[i][2]=0.f; acc[i][3]=0.f; }
        #pragma unroll
        for(int i=0;i<2;i++)
            #pragma unroll
            for(int ks=0;ks<4;ks++)
                acc[i] = __builtin_amdgcn_mfma_f32_16x16x32_bf16(A[ks], B[i][ks], acc[i], 0, 0, 0);
        #pragma unroll
        for(int i=0;i<2;i++){
            int head = 2*wv + i;
            #pragma unroll
            for(int r=0;r<4;r++){
                float a = acc[i][r] + bc[i];
                int node = n0 + quad*4 + r;
                h[(size_t)node*HIDN + head*16 + sl] = f2bf(a);
                float p0 = a*ade[i], p1 = a*asv[i], p2 = a*adv[i];
                #pragma unroll
                for(int m=8;m>=1;m>>=1){
                    p0 += __shfl_xor(p0, m);
                    p1 += __shfl_xor(p1, m);
                    p2 += __shfl_xor(p2, m);
                }
                if(sl == 0){
                    adst_em[node*NHEAD + head] = p0;
                    asrc_mm[node*NHEAD + head] = p1;
                    adst_mm[node*NHEAD + head] = p2;
                }
            }
        }
    }
}

// ---------------- pass A: bin edges into dst-buckets; in-block bucket scan, LDS-staged,
// coalesced writeout. staged entry = (dstLow << 17) | src
__global__ __launch_bounds__(256) void bin_pass(
    const int* __restrict__ bcnt_em, const int* __restrict__ bcnt_mm,
    const int* __restrict__ src_em, const int* __restrict__ dst_em, int nE_em,
    int* __restrict__ bcur_em, uint32* __restrict__ st_em,
    const int* __restrict__ src_mm, const int* __restrict__ dst_mm, int nE_mm,
    int* __restrict__ bcur_mm, uint32* __restrict__ st_mm)
{
    __shared__ int cnt[NBK];
    __shared__ int lexcl[NBK];
    __shared__ int gbase[NBK];
    __shared__ int sbE[NBK];
    __shared__ int sbM[NBK];
    __shared__ int wsumA[4];
    __shared__ int wsumB[4];
    __shared__ uint32 stg[BCH];
    __shared__ unsigned short bid[BCH];
    int t = threadIdx.x, l = t & 63, w = t >> 6;
    // ---- block-local exclusive scan of bcnt_em -> sbE
    {
        int vA = bcnt_em[t];
        int xA = vA;
        #pragma unroll
        for(int off=1; off<64; off<<=1){ int y = __shfl_up(xA, off); if(l >= off) xA += y; }
        if(l == 63) wsumA[w] = xA;
        int iB = 256 + t;
        int vB = (iB < NBK) ? bcnt_em[iB] : 0;
        int xB = vB;
        #pragma unroll
        for(int off=1; off<64; off<<=1){ int y = __shfl_up(xB, off); if(l >= off) xB += y; }
        if(l == 63) wsumB[w] = xB;
        __syncthreads();
        int baseA = 0; for(int k=0;k<w;k++) baseA += wsumA[k];
        int totA = wsumA[0]+wsumA[1]+wsumA[2]+wsumA[3];
        int baseB = 0; for(int k=0;k<w;k++) baseB += wsumB[k];
        sbE[t] = baseA + xA - vA;
        if(iB < NBK) sbE[iB] = totA + baseB + xB - vB;
        __syncthreads();
    }
    // ---- same for bcnt_mm -> sbM
    {
        int vA = bcnt_mm[t];
        int xA = vA;
        #pragma unroll
        for(int off=1; off<64; off<<=1){ int y = __shfl_up(xA, off); if(l >= off) xA += y; }
        if(l == 63) wsumA[w] = xA;
        int iB = 256 + t;
        int vB = (iB < NBK) ? bcnt_mm[iB] : 0;
        int xB = vB;
        #pragma unroll
        for(int off=1; off<64; off<<=1){ int y = __shfl_up(xB, off); if(l >= off) xB += y; }
        if(l == 63) wsumB[w] = xB;
        __syncthreads();
        int baseA = 0; for(int k=0;k<w;k++) baseA += wsumA[k];
        int totA = wsumA[0]+wsumA[1]+wsumA[2]+wsumA[3];
        int baseB = 0; for(int k=0;k<w;k++) baseB += wsumB[k];
        sbM[t] = baseA + xA - vA;
        if(iB < NBK) sbM[iB] = totA + baseB + xB - vB;
    }
    for(int i=t;i<NBK;i+=256) cnt[i] = 0;

    int nch_em = (nE_em + BCH - 1)/BCH;
    int nch_mm = (nE_mm + BCH - 1)/BCH;
    int ntot = nch_em + nch_mm;
    for(int c = blockIdx.x; c < ntot; c += gridDim.x){
        bool em = c < nch_em;
        const int* src = em ? src_em : src_mm;
        const int* dst = em ? dst_em : dst_mm;
        int nE   = em ? nE_em : nE_mm;
        int* bcur = em ? bcur_em : bcur_mm;
        uint32* st = em ? st_em : st_mm;
        const int* sb = em ? sbE : sbM;
        int cc = em ? c : c - nch_em;
        int s = cc*BCH;
        int e = s + BCH; if(e > nE) e = nE;
        int len = e - s;
        int n4 = len >> 2;
        const int4* d4 = (const int4*)(dst + s);
        const int4* s4 = (const int4*)(src + s);
        __syncthreads();                       // cnt zeroed (init or prev iter)
        // histogram
        for(int i=t;i<n4;i+=256){
            int4 v = d4[i];
            atomicAdd(&cnt[v.x>>SH],1); atomicAdd(&cnt[v.y>>SH],1);
            atomicAdd(&cnt[v.z>>SH],1); atomicAdd(&cnt[v.w>>SH],1);
        }
        for(int i = s + (n4<<2) + t; i < e; i += 256) atomicAdd(&cnt[dst[i]>>SH], 1);
        __syncthreads();
        // scan 391 chunk counts (two 256-wide segments), reserve global runs, zero cnt
        {
            int vA = cnt[t];
            int xA = vA;
            #pragma unroll
            for(int off=1; off<64; off<<=1){ int y = __shfl_up(xA, off); if(l >= off) xA += y; }
            if(l == 63) wsumA[w] = xA;
            __syncthreads();
            int baseA = 0;
            for(int k=0;k<w;k++) baseA += wsumA[k];
            int exA = baseA + xA - vA;
            int totA = wsumA[0]+wsumA[1]+wsumA[2]+wsumA[3];
            int idxB = 256 + t;
            int vB = (idxB < NBK) ? cnt[idxB] : 0;
            int xB = vB;
            #pragma unroll
            for(int off=1; off<64; off<<=1){ int y = __shfl_up(xB, off); if(l >= off) xB += y; }
            if(l == 63) wsumB[w] = xB;
            __syncthreads();
            int baseB = 0;
            for(int k=0;k<w;k++) baseB += wsumB[k];
            int exB = totA + baseB + xB - vB;
            lexcl[t] = exA;
            gbase[t] = sb[t] + atomicAdd(&bcur[t], vA);
            cnt[t] = 0;
            if(idxB < NBK){
                lexcl[idxB] = exB;
                gbase[idxB] = sb[idxB] + atomicAdd(&bcur[idxB], vB);
                cnt[idxB] = 0;
            }
        }
        __syncthreads();
        // replay into LDS staging (ordered by bucket)
        for(int i=t;i<n4;i+=256){
            int4 dv = d4[i];
            int4 sv = s4[i];
            int b, p;
            b = dv.x>>SH; p = lexcl[b] + atomicAdd(&cnt[b],1);
            stg[p] = ((uint32)(dv.x & ((1<<SH)-1)) << 17) | (uint32)sv.x; bid[p] = (unsigned short)b;
            b = dv.y>>SH; p = lexcl[b] + atomicAdd(&cnt[b],1);
            stg[p] = ((uint32)(dv.y & ((1<<SH)-1)) << 17) | (uint32)sv.y; bid[p] = (unsigned short)b;
            b = dv.z>>SH; p = lexcl[b] + atomicAdd(&cnt[b],1);
            stg[p] = ((uint32)(dv.z & ((1<<SH)-1)) << 17) | (uint32)sv.z; bid[p] = (unsigned short)b;
            b = dv.w>>SH; p = lexcl[b] + atomicAdd(&cnt[b],1);
            stg[p] = ((uint32)(dv.w & ((1<<SH)-1)) << 17) | (uint32)sv.w; bid[p] = (unsigned short)b;
        }
        for(int i = s + (n4<<2) + t; i < e; i += 256){
            int d = dst[i];
            int b = d >> SH;
            int p = lexcl[b] + atomicAdd(&cnt[b], 1);
            stg[p] = ((uint32)(d & ((1<<SH)-1)) << 17) | (uint32)src[i]; bid[p] = (unsigned short)b;
        }
        __syncthreads();
        // coalesced writeout: consecutive i -> same bucket run -> consecutive global addr
        for(int i=t;i<len;i+=256){
            int b = bid[i];
            st[gbase[b] + (i - lexcl[b])] = stg[i];
        }
        __syncthreads();
        for(int i=t;i<NBK;i+=256) cnt[i] = 0;
    }
}

// ---------------- pass B: per bucket — in-block scan for beg/end, offsets, LDS-ordered
// CSR segment, coalesced out
__global__ __launch_bounds__(256) void place_pass(
    const int* __restrict__ bcnt_em, const uint32* __restrict__ st_em,
    int* __restrict__ csr_em, int* __restrict__ offs_em, int nE_em,
    const int* __restrict__ bcnt_mm, const uint32* __restrict__ st_mm,
    int* __restrict__ csr_mm, int* __restrict__ offs_mm, int nE_mm)
{
    __shared__ int cnt[256];
    __shared__ int wsA[4], wsB[4];
    __shared__ int cur[256];
    __shared__ int sb2[NBK+1];
    __shared__ uint32 loc[LOCN];
    int b = blockIdx.x;
    bool em = b < NBK;
    const int* bc        = em ? bcnt_em : bcnt_mm;
    const uint32* stp    = em ? st_em : st_mm;
    int* csr             = em ? csr_em : csr_mm;
    int* offs            = em ? offs_em : offs_mm;
    int nE               = em ? nE_em : nE_mm;
    int bk = em ? b : b - NBK;
    int d0 = bk << SH;
    int t = threadIdx.x, l = t & 63, w = t >> 6;
    int nd = N_MATN - d0; if(nd > 256) nd = 256;
    cnt[t] = 0;
    // ---- scan bucket counts -> sb2 (exclusive), sb2[NBK] = nE
    {
        int vA = bc[t];
        int xA = vA;
        #pragma unroll
        for(int off=1; off<64; off<<=1){ int y = __shfl_up(xA, off); if(l >= off) xA += y; }
        if(l == 63) wsA[w] = xA;
        int iB = 256 + t;
        int vB = (iB < NBK) ? bc[iB] : 0;
        int xB = vB;
        #pragma unroll
        for(int off=1; off<64; off<<=1){ int y = __shfl_up(xB, off); if(l >= off) xB += y; }
        if(l == 63) wsB[w] = xB;
        __syncthreads();
        int baseA = 0; for(int k=0;k<w;k++) baseA += wsA[k];
        int totA = wsA[0]+wsA[1]+wsA[2]+wsA[3];
        int baseB = 0; for(int k=0;k<w;k++) baseB += wsB[k];
        sb2[t] = baseA + xA - vA;
        if(iB < NBK) sb2[iB] = totA + baseB + xB - vB;
        if(t == 0) sb2[NBK] = nE;
        __syncthreads();
    }
    int beg = sb2[bk], end = sb2[bk+1];
    int len = end - beg;
    if(bk == 0 && t == 0) offs[N_MATN] = nE;
    for(int i = beg + t; i < end; i += 256)
        atomicAdd(&cnt[stp[i] >> 17], 1);
    __syncthreads();
    int v = cnt[t];
    int x = v;
    #pragma unroll
    for(int off=1; off<64; off<<=1){ int y = __shfl_up(x, off); if(l >= off) x += y; }
    if(l == 63) wsA[w] = x;
    __syncthreads();
    int base = 0;
    for(int k=0;k<w;k++) base += wsA[k];
    int excl = base + x - v;            // local (0-based) exclusive prefix
    if(t < nd) offs[d0 + t] = beg + excl;
    if(len <= LOCN){
        cur[t] = excl;
        __syncthreads();
        for(int i = beg + t; i < end; i += 256){
            uint32 vv = stp[i];
            int dl = (int)(vv >> 17);
            int p = atomicAdd(&cur[dl], 1);
            loc[p] = vv & 0x1FFFFu;
        }
        __syncthreads();
        for(int i = t; i < len; i += 256)
            csr[beg + i] = (int)loc[i];
    } else {
        cur[t] = beg + excl;
        __syncthreads();
        for(int i = beg + t; i < end; i += 256){
            uint32 vv = stp[i];
            int dl = (int)(vv >> 17);
            int p = atomicAdd(&cur[dl], 1);
            csr[p] = (int)(vv & 0x1FFFFu);
        }
    }
}

// ---------------- aggregation: 16 lanes/edge, 8 edges per wave-iteration (R4 version)
__global__ __launch_bounds__(256) void agg_both(
    const int* __restrict__ offs_em, const int* __restrict__ csr_em,
    const ushort16* __restrict__ h_elem, const float* __restrict__ asrc_em,
    const float* __restrict__ adst_em, ushort16* __restrict__ o_em,
    const int* __restrict__ offs_mm, const int* __restrict__ csr_mm,
    const ushort16* __restrict__ h_mat, const float* __restrict__ asrc_mm,
    const float* __restrict__ adst_mm, ushort16* __restrict__ o_mm)
{
    int lane = threadIdx.x & 63;
    int g = lane >> 4;            // edge slot 0..3
    int q = lane & 15;            // channel quad: channels [q*8, q*8+8)
    int hd = q >> 1;              // head for these channels
    int w = (blockIdx.x*blockDim.x + threadIdx.x) >> 6;
    int nw = (gridDim.x*blockDim.x) >> 6;
    for(int nid = w; nid < 2*N_MATN; nid += nw){
        int nidu = __builtin_amdgcn_readfirstlane(nid);
        bool em = nidu < N_MATN;
        int d = em ? nidu : nidu - N_MATN;
        const int*    offs = em ? offs_em : offs_mm;
        const int*    csr  = em ? csr_em  : csr_mm;
        const uint32* hs   = (const uint32*)(em ? h_elem : h_mat);
        const float*  asp  = em ? asrc_em : asrc_mm;
        const float*  adp  = em ? adst_em : adst_mm;
        uint32*       op   = (uint32*)(em ? o_em : o_mm);
        int beg = offs[d], end = offs[d+1];
        float ad = adp[(unsigned)(d*NHEAD + hd)];
        float denA = 0.f, denB = 0.f;
        float nloA[4] = {0.f,0.f,0.f,0.f}, nhiA[4] = {0.f,0.f,0.f,0.f};
        float nloB[4] = {0.f,0.f,0.f,0.f}, nhiB[4] = {0.f,0.f,0.f,0.f};
        for(int j0 = beg; j0 < end; j0 += 8){
            int e0 = j0 + g, e1 = j0 + 4 + g;
            bool v0 = e0 < end, v1 = e1 < end;
            int s0 = csr[(unsigned)(v0 ? e0 : end - 1)];
            int s1 = csr[(unsigned)(v1 ? e1 : end - 1)];
            // issue all four gathers before any dependent math
            float a0 = asp[(unsigned)(s0*NHEAD + hd)];
            float a1 = asp[(unsigned)(s1*NHEAD + hd)];
            const uint4 h0 = *(const uint4*)(hs + (unsigned)(s0*64 + q*4));
            const uint4 h1 = *(const uint4*)(hs + (unsigned)(s1*64 + q*4));
            float al0 = a0 + ad; al0 = fmaxf(al0, 0.2f*al0);
            float ex0 = __expf(al0); ex0 = v0 ? ex0 : 0.f;
            float al1 = a1 + ad; al1 = fmaxf(al1, 0.2f*al1);
            float ex1 = __expf(al1); ex1 = v1 ? ex1 : 0.f;
            denA += ex0; denB += ex1;
            nloA[0] += blo(h0.x)*ex0; nhiA[0] += bhi(h0.x)*ex0;
            nloA[1] += blo(h0.y)*ex0; nhiA[1] += bhi(h0.y)*ex0;
            nloA[2] += blo(h0.z)*ex0; nhiA[2] += bhi(h0.z)*ex0;
            nloA[3] += blo(h0.w)*ex0; nhiA[3] += bhi(h0.w)*ex0;
            nloB[0] += blo(h1.x)*ex1; nhiB[0] += bhi(h1.x)*ex1;
            nloB[1] += blo(h1.y)*ex1; nhiB[1] += bhi(h1.y)*ex1;
            nloB[2] += blo(h1.z)*ex1; nhiB[2] += bhi(h1.z)*ex1;
            nloB[3] += blo(h1.w)*ex1; nhiB[3] += bhi(h1.w)*ex1;
        }
        float den = denA + denB;
        den += __shfl_xor(den, 16); den += __shfl_xor(den, 32);
        float nlo[4], nhi[4];
        #pragma unroll
        for(int k=0;k<4;k++){
            nlo[k] = nloA[k] + nloB[k];
            nhi[k] = nhiA[k] + nhiB[k];
            nlo[k] += __shfl_xor(nlo[k], 16); nlo[k] += __shfl_xor(nlo[k], 32);
            nhi[k] += __shfl_xor(nhi[k], 16); nhi[k] += __shfl_xor(nhi[k], 32);
        }
        if(g == 0){
            float rdn = 1.0f/(den + 1e-16f);
            uint4 pk;
            pk.x = pack2(fmaxf(nlo[0]*rdn, 0.f), fmaxf(nhi[0]*rdn, 0.f));
            pk.y = pack2(fmaxf(nlo[1]*rdn, 0.f), fmaxf(nhi[1]*rdn, 0.f));
            pk.z = pack2(fmaxf(nlo[2]*rdn, 0.f), fmaxf(nhi[2]*rdn, 0.f));
            pk.w = pack2(fmaxf(nlo[3]*rdn, 0.f), fmaxf(nhi[3]*rdn, 0.f));
            *(uint4*)(op + (size_t)d*64 + q*4) = pk;
        }
    }
}

// ---------------- semantic scores — MFMA; block partials atomically into scores[]
__global__ __launch_bounds__(256) void score_mfma(
    const ushort16* __restrict__ o_em, const ushort16* __restrict__ o_mm,
    const float* __restrict__ Wk, const float* __restrict__ bkv,
    const float* __restrict__ qv, float* __restrict__ scores)
{
    int tid = threadIdx.x;
    int wv = tid >> 6, lane = tid & 63, quad = lane >> 4, sl = lane & 15;
    bf16x8 B[2][4];
    float bkc[2], qc[2];
    #pragma unroll
    for(int i=0;i<2;i++){
        int c = (2*wv+i)*16 + sl;
        const float* wr = Wk + c*HIDN;
        #pragma unroll
        for(int ks=0;ks<4;ks++) B[i][ks] = cvt8(wr + ks*32 + quad*8);
        bkc[i] = bkv[c]; qc[i] = qv[c];
    }
    float se = 0.f, sm = 0.f;
    for(int s = blockIdx.x; s < NSTRIPS; s += gridDim.x){
        int n0 = s*16;
        const bf16x8* rowE = (const bf16x8*)(o_em + (size_t)(n0+sl)*HIDN);
        const bf16x8* rowM = (const bf16x8*)(o_mm + (size_t)(n0+sl)*HIDN);
        bf16x8 AE[4], AM[4];
        #pragma unroll
        for(int ks=0;ks<4;ks++){
            AE[ks] = rowE[ks*4 + quad];
            AM[ks] = rowM[ks*4 + quad];
        }
        f32x4 aE[2], aM[2];
        #pragma unroll
        for(int i=0;i<2;i++){
            aE[i][0]=0.f;aE[i][1]=0.f;aE[i][2]=0.f;aE[i][3]=0.f;
            aM[i][0]=0.f;aM[i][1]=0.f;aM[i][2]=0.f;aM[i][3]=0.f;
        }
        #pragma unroll
        for(int i=0;i<2;i++)
            #pragma unroll
            for(int ks=0;ks<4;ks++){
                aE[i] = __builtin_amdgcn_mfma_f32_16x16x32_bf16(AE[ks], B[i][ks], aE[i], 0, 0, 0);
                aM[i] = __builtin_amdgcn_mfma_f32_16x16x32_bf16(AM[ks], B[i][ks], aM[i], 0, 0, 0);
            }
        #pragma unroll
        for(int i=0;i<2;i++)
            #pragma unroll
            for(int r=0;r<4;r++){
                se += qc[i]*tanhf(aE[i][r] + bkc[i]);
                sm += qc[i]*tanhf(aM[i][r] + bkc[i]);
            }
    }
    #pragma unroll
    for(int m=32;m>=1;m>>=1){ se += __shfl_xor(se,m); sm += __shfl_xor(sm,m); }
    __shared__ float red[8];
    if(lane==0){ red[wv*2]=se; red[wv*2+1]=sm; }
    __syncthreads();
    if(tid==0){
        atomicAdd(&scores[0], red[0]+red[2]+red[4]+red[6]);
        atomicAdd(&scores[1], red[1]+red[3]+red[5]+red[7]);
    }
}

// ---------------- final — MFMA GEMM: out = (a0*o_em + a1*o_mm) @ Wl^T + bl, no LDS
__global__ __launch_bounds__(256) void final_mfma(
    const ushort16* __restrict__ o_em, const ushort16* __restrict__ o_mm,
    const float* __restrict__ Wl, const float* __restrict__ blv,
    const float* __restrict__ scores, float* __restrict__ out)
{
    int tid = threadIdx.x;
    int lane = tid & 63, quad = lane >> 4, sl = lane & 15;
    // B fragments: 4 col-groups (64 cols) x 4 k-slices; layout identical to proj_mat
    bf16x8 B[4][4];
    float blc[4];
    #pragma unroll
    for(int i=0;i<4;i++){
        int c = i*16 + sl;
        const float* wr = Wl + c*HIDN;
        #pragma unroll
        for(int ks=0;ks<4;ks++) B[i][ks] = cvt8(wr + ks*32 + quad*8);
        blc[i] = blv[c];
    }
    float s0 = scores[0]*(1.0f/N_MATN), s1 = scores[1]*(1.0f/N_MATN);
    float mx = fmaxf(s0,s1);
    float e0 = __expf(s0-mx), e1 = __expf(s1-mx);
    float inv = 1.0f/(e0+e1);
    float a0 = e0*inv, a1 = e1*inv;
    int gw = (blockIdx.x*blockDim.x + tid) >> 6;
    int nwv = (gridDim.x*blockDim.x) >> 6;
    for(int s = gw; s < NSTRIPS; s += nwv){
        int n0 = s*16;
        const uint4* rowE = (const uint4*)((const uint32*)o_em + (size_t)(n0+sl)*64);
        const uint4* rowM = (const uint4*)((const uint32*)o_mm + (size_t)(n0+sl)*64);
        bf16x8 A[4];
        #pragma unroll
        for(int ks=0;ks<4;ks++){
            uint4 e = rowE[ks*4 + quad];   // channels ks*32+quad*8 .. +8
            uint4 m = rowM[ks*4 + quad];
            bf16x8 a;
            a[0] = (short)f2bf(a0*blo(e.x)+a1*blo(m.x));
            a[1] = (short)f2bf(a0*bhi(e.x)+a1*bhi(m.x));
            a[2] = (short)f2bf(a0*blo(e.y)+a1*blo(m.y));
            a[3] = (short)f2bf(a0*bhi(e.y)+a1*bhi(m.y));
            a[4] = (short)f2bf(a0*blo(e.z)+a1*blo(m.z));
            a[5] = (short)f2bf(a0*bhi(e.z)+a1*bhi(m.z));
            a[6] = (short)f2bf(a0*blo(e.w)+a1*blo(m.w));
            a[7] = (short)f2bf(a0*bhi(e.w)+a1*bhi(m.w));
            A[ks] = a;
        }
        f32x4 acc[4];
        #pragma unroll
        for(int i=0;i<4;i++){ acc[i][0]=0.f; acc[i][1]=0.f; acc[i][2]=0.f; acc[i][3]=0.f; }
        #pragma unroll
        for(int i=0;i<4;i++)
            #pragma unroll
            for(int ks=0;ks<4;ks++)
                acc[i] = __builtin_amdgcn_mfma_f32_16x16x32_bf16(A[ks], B[i][ks], acc[i], 0, 0, 0);
        #pragma unroll
        for(int i=0;i<4;i++)
            #pragma unroll
            for(int r=0;r<4;r++)
                out[(size_t)(n0 + quad*4 + r)*OUTC + i*16 + sl] = acc[i][r] + blc[i];
    }
}

extern "C" void kernel_launch(void* const* d_in, const int* in_sizes, int n_in,
                              void* d_out, int out_size, void* d_ws, size_t ws_size,
                              hipStream_t stream)
{
    const float* x_mat    = (const float*)d_in[0];
    const float* x_elem   = (const float*)d_in[1];
    const float* W_pm     = (const float*)d_in[2];
    const float* b_pm     = (const float*)d_in[3];
    const float* W_pe     = (const float*)d_in[4];
    const float* b_pe     = (const float*)d_in[5];
    const float* a_se     = (const float*)d_in[6];
    const float* a_de     = (const float*)d_in[7];
    const float* a_sm     = (const float*)d_in[8];
    const float* a_dm     = (const float*)d_in[9];
    const float* Wk       = (const float*)d_in[10];
    const float* bk       = (const float*)d_in[11];
    const float* qv       = (const float*)d_in[12];
    const float* Wl       = (const float*)d_in[13];
    const float* bl       = (const float*)d_in[14];
    const int* src_em     = (const int*)d_in[15];
    const int* dst_em     = (const int*)d_in[16];
    const int* src_mm     = (const int*)d_in[17];
    const int* dst_mm     = (const int*)d_in[18];
    int nE_em = in_sizes[15];
    int nE_mm = in_sizes[17];

    char* ws = (char*)d_ws;
    size_t off = 0;
    auto alloc = [&](size_t bytes) -> void* {
        void* p = ws + off; off += (bytes + 255) & ~size_t(255); return p;
    };
    ushort16* h_mat   = (ushort16*)alloc((size_t)N_MATN*HIDN*2);
    ushort16* h_elem  = (ushort16*)alloc((size_t)N_ELEMN*HIDN*2);
    float*    asrcEM  = (float*)   alloc((size_t)N_ELEMN*NHEAD*4);
    float*    adstEM  = (float*)   alloc((size_t)N_MATN*NHEAD*4);
    float*    asrcMM  = (float*)   alloc((size_t)N_MATN*NHEAD*4);
    float*    adstMM  = (float*)   alloc((size_t)N_MATN*NHEAD*4);
    int*      offs_em = (int*)     alloc((size_t)(N_MATN+1)*4);
    int*      offs_mm = (int*)     alloc((size_t)(N_MATN+1)*4);
    int*      csr_em  = (int*)     alloc((size_t)1000000*4);
    int*      csr_mm  = (int*)     alloc((size_t)2000000*4);
    ushort16* o_em    = (ushort16*)alloc((size_t)N_MATN*HIDN*2);
    ushort16* o_mm    = (ushort16*)alloc((size_t)N_MATN*HIDN*2);
    size_t zero_start = off;
    int*      bcnt_em = (int*)     alloc((size_t)NBK*4);
    int*      bcnt_mm = (int*)     alloc((size_t)NBK*4);
    int*      bcur_em = (int*)     alloc((size_t)NBK*4);   // zero-based chunk cursors
    int*      bcur_mm = (int*)     alloc((size_t)NBK*4);
    float*    scores  = (float*)   alloc(256);
    size_t zero_bytes = off - zero_start;

    // staged (bucketed) edge buffers alias o_em: dead before agg_both writes o_em.
    // (nE_em + nE_mm) * 4B = 12 MB <= 25.6 MB of o_em.
    uint32* st_em = (uint32*)o_em;
    uint32* st_mm = st_em + nE_em;

    hipMemsetAsync(ws + zero_start, 0, zero_bytes, stream);

    proj_all<<<N_ELEMN + MATBLK + CNTBLK, 256, 0, stream>>>(
        x_elem, W_pe, b_pe, a_se, h_elem, asrcEM,
        x_mat, W_pm, b_pm, a_de, a_sm, a_dm,
        h_mat, adstEM, asrcMM, adstMM,
        dst_em, nE_em, bcnt_em, dst_mm, nE_mm, bcnt_mm);

    int nch = (nE_em + BCH - 1)/BCH + (nE_mm + BCH - 1)/BCH;
    bin_pass<<<nch, 256, 0, stream>>>(bcnt_em, bcnt_mm,
                                      src_em, dst_em, nE_em, bcur_em, st_em,
                                      src_mm, dst_mm, nE_mm, bcur_mm, st_mm);
    place_pass<<<2*NBK, 256, 0, stream>>>(bcnt_em, st_em, csr_em, offs_em, nE_em,
                                          bcnt_mm, st_mm, csr_mm, offs_mm, nE_mm);

    agg_both<<<4096, 256, 0, stream>>>(offs_em, csr_em, h_elem, asrcEM, adstEM, o_em,
                                       offs_mm, csr_mm, h_mat, asrcMM, adstMM, o_mm);

    score_mfma<<<1024, 256, 0, stream>>>(o_em, o_mm, Wk, bk, qv, scores);
    final_mfma<<<1563, 256, 0, stream>>>(o_em, o_mm, Wl, bl, scores, (float*)d_out);
}